// Round 2
// 56876.648 us; speedup vs baseline: 1.6286x; 1.6286x over previous
//
#include <hip/hip_runtime.h>
#include <hip/hip_bf16.h>

// tanh-approx GELU (JAX default) and its exact derivative
__device__ __forceinline__ float gelu_f(float x) {
  const float c = 0.7978845608028654f;
  float u = c * (x + 0.044715f * x * x * x);
  float t = tanhf(u);
  return 0.5f * x * (1.f + t);
}
__device__ __forceinline__ float gelu_grad_f(float x) {
  const float c = 0.7978845608028654f;
  float x2 = x * x;
  float u = c * (x + 0.044715f * x2 * x);
  float t = tanhf(u);
  return 0.5f * (1.f + t) + 0.5f * x * (1.f - t * t) * c * (1.f + 0.134145f * x2);
}

// ---------------------------------------------------------------------------
// Tiled fp32 GEMM (forward path). 64x64 tile, 16-deep K panel.
// ---------------------------------------------------------------------------
template<bool TRANSB, int ACT>
__global__ __launch_bounds__(256) void gemm_k(
    const float* __restrict__ A, const float* __restrict__ B, float* __restrict__ C,
    float* __restrict__ Zbuf, const float* __restrict__ bias,
    int M, int N, int K, int lda, int ldb,
    int P, int bsRows, int rowOff,
    const float* __restrict__ ci, int ciP, int ciBs, int ciOff,
    const float* __restrict__ delta, float gscale)
{
  __shared__ float As[16][68];
  __shared__ float Bs[16][68];
  const int bm = blockIdx.y * 64, bn = blockIdx.x * 64;
  const int tid = threadIdx.x;
  const int tr = tid >> 4, tc = tid & 15;
  float acc[4][4] = {};
  for (int k0 = 0; k0 < K; k0 += 16) {
    {
      const int e = tid * 4;
      const int m = e >> 4, kk = e & 15;
      const int gm = bm + m;
      const bool mv = gm < M;
      const long grow = (long)(gm / P) * bsRows + rowOff + (gm % P);
      const float* ap = A + grow * lda + k0 + kk;
      #pragma unroll
      for (int i = 0; i < 4; i++) {
        float v = 0.f;
        if (mv) v = ap[i];
        As[kk + i][m] = v;
      }
    }
    if (!TRANSB) {
      const int e = tid * 4;
      const int kk = e >> 6, n = e & 63;
      const int gn = bn + n;
      const float* bp = B + (long)(k0 + kk) * ldb + gn;
      #pragma unroll
      for (int i = 0; i < 4; i++) Bs[kk][n + i] = bp[i];
    } else {
      const int e = tid * 4;
      const int n = e >> 4, kk = e & 15;
      const int gn = bn + n;
      const float* bp = B + (long)gn * ldb + k0 + kk;
      #pragma unroll
      for (int i = 0; i < 4; i++) Bs[kk + i][n] = bp[i];
    }
    __syncthreads();
    #pragma unroll
    for (int kk = 0; kk < 16; kk++) {
      float a[4], b[4];
      #pragma unroll
      for (int i = 0; i < 4; i++) a[i] = As[kk][tr * 4 + i];
      #pragma unroll
      for (int j = 0; j < 4; j++) b[j] = Bs[kk][tc * 4 + j];
      #pragma unroll
      for (int i = 0; i < 4; i++)
        #pragma unroll
        for (int j = 0; j < 4; j++) acc[i][j] += a[i] * b[j];
    }
    __syncthreads();
  }
  #pragma unroll
  for (int i = 0; i < 4; i++) {
    const int m = bm + tr * 4 + i;
    if (m >= M) continue;
    #pragma unroll
    for (int j = 0; j < 4; j++) {
      const int n = bn + tc * 4 + j;
      if (n >= N) continue;
      float v = acc[i][j];
      if (bias) v += bias[n];
      if (ACT == 1) {
        if (Zbuf) Zbuf[(long)m * N + n] = v;
        v = gelu_f(v);
      } else if (ACT == 2) {
        const long crow = (long)(m / ciP) * ciBs + ciOff + (m % ciP);
        const float tgt = ci[crow * 1024 + n] + delta[(m / ciP) * 1024 + n];
        v = gscale * (v - tgt);
      } else if (ACT == 3) {
        v = v * gelu_grad_f(Zbuf[(long)m * N + n]);
      }
      C[(long)m * N + n] = v;
    }
  }
}

// ---------------------------------------------------------------------------
// Flash-style causal attention (unchanged).
// ---------------------------------------------------------------------------
__global__ __launch_bounds__(256) void attn_kernel(
    const float* __restrict__ Q, const float* __restrict__ K,
    const float* __restrict__ V, float* __restrict__ ctx)
{
  const int S = 2048, D = 1024;
  const int qt = blockIdx.x, h = blockIdx.y, b = blockIdx.z;
  const int q0 = qt * 64;
  __shared__ float Qs[64][65];
  __shared__ float Ks[32][65];
  __shared__ float Vs[32][65];
  __shared__ float Ss[64][33];
  const int tid = threadIdx.x;
  for (int e = tid; e < 4096; e += 256) {
    int r = e >> 6, d = e & 63;
    Qs[r][d] = Q[(long)(b * S + q0 + r) * D + h * 64 + d];
  }
  const int r = tid >> 2;
  const int g = tid & 3;
  const int dg8 = g * 8;
  const int dg16 = g * 16;
  float acc[16];
  #pragma unroll
  for (int i = 0; i < 16; i++) acc[i] = 0.f;
  float mrow = -1e30f, lrow = 0.f;
  for (int k0 = 0; k0 < q0 + 64; k0 += 32) {
    __syncthreads();
    for (int e = tid; e < 2048; e += 256) {
      int rr = e >> 6, d = e & 63;
      Ks[rr][d] = K[(long)(b * S + k0 + rr) * D + h * 64 + d];
      Vs[rr][d] = V[(long)(b * S + k0 + rr) * D + h * 64 + d];
    }
    __syncthreads();
    float sc[8];
    #pragma unroll
    for (int j = 0; j < 8; j++) sc[j] = 0.f;
    for (int d = 0; d < 64; d++) {
      float qd = Qs[r][d];
      #pragma unroll
      for (int j = 0; j < 8; j++) sc[j] += qd * Ks[dg8 + j][d];
    }
    float tmax = -1e30f;
    #pragma unroll
    for (int j = 0; j < 8; j++) {
      sc[j] *= 0.125f;
      if (k0 + dg8 + j > q0 + r) sc[j] = -1e30f;
      tmax = fmaxf(tmax, sc[j]);
    }
    tmax = fmaxf(tmax, __shfl_xor(tmax, 1));
    tmax = fmaxf(tmax, __shfl_xor(tmax, 2));
    const float newm = fmaxf(mrow, tmax);
    const float scale = __expf(mrow - newm);
    float psum = 0.f;
    #pragma unroll
    for (int j = 0; j < 8; j++) {
      sc[j] = __expf(sc[j] - newm);
      psum += sc[j];
    }
    psum += __shfl_xor(psum, 1);
    psum += __shfl_xor(psum, 2);
    lrow = lrow * scale + psum;
    mrow = newm;
    #pragma unroll
    for (int i = 0; i < 16; i++) acc[i] *= scale;
    #pragma unroll
    for (int j = 0; j < 8; j++) Ss[r][dg8 + j] = sc[j];
    __syncthreads();
    for (int c = 0; c < 32; c++) {
      float p = Ss[r][c];
      #pragma unroll
      for (int i = 0; i < 16; i++) acc[i] += p * Vs[c][dg16 + i];
    }
  }
  const float inv = 1.f / lrow;
  #pragma unroll
  for (int i = 0; i < 16; i++)
    ctx[(long)(b * S + q0 + r) * D + h * 64 + dg16 + i] = acc[i] * inv;
}

// Per-chunk teach means for both levels (unchanged).
__global__ void compute_deltas(const float* __restrict__ teach,
                               float* __restrict__ dF, float* __restrict__ dS)
{
  const int nF = 128 * 2048;
  const int nS = 32 * 2048;
  int t = blockIdx.x * blockDim.x + threadIdx.x;
  if (t < nF) {
    int c = t >> 11, b = (t >> 10) & 1, d = t & 1023;
    long base = ((long)(b * 2048 + c * 16)) * 1024 + d;
    float s = 0.f;
    for (int k = 0; k < 16; k++) s += teach[base + (long)k * 1024];
    dF[t] = s * (1.f / 16.f);
  } else if (t < nF + nS) {
    int u = t - nF;
    int c = u >> 11, b = (u >> 10) & 1, d = u & 1023;
    long base = ((long)(b * 2048 + c * 64)) * 1024 + d;
    float s = 0.f;
    for (int k = 0; k < 64; k++) s += teach[base + (long)k * 1024];
    dS[u] = s * (1.f / 64.f);
  }
}

// ---------------------------------------------------------------------------
// Self-contained grid barrier: monotonic counter, no cooperative-launch
// dependency. Co-residency guaranteed by capacity (grid=256 blocks = #CUs,
// 1 block/CU by LDS+thread budget). Bailout prevents container hangs.
// ---------------------------------------------------------------------------
__device__ __forceinline__ void grid_bar(int* cnt, int target) {
  __threadfence();
  __syncthreads();
  if (threadIdx.x == 0) {
    atomicAdd(cnt, 1);
    int spins = 0;
    while (atomicAdd(cnt, 0) < target) {
      __builtin_amdgcn_s_sleep(2);
      if (++spins > (1 << 21)) break;   // ~0.5s bailout: corrupt, don't hang
    }
  }
  __syncthreads();
  __threadfence();
}

// ---------------------------------------------------------------------------
// Fused TTT scan: ONE persistent kernel per level. 256 blocks x 512 threads.
// Block b owns: W1 cols [16b,16b+16), W2 rows [16b,16b+16), b1[16b..+16),
//               and (write side) b2 / G columns for the p2 phase.
// Per chunk: p1 (z,a -> abuf) | BAR | p2 (pred->G, b2) | BAR |
//            p3 (dZ + fused W2-row update + b1) | p4a (W1 update).
// No barrier at chunk end (ownership makes it race-free).
// ---------------------------------------------------------------------------
template<int P, int NC>
__global__ __launch_bounds__(512, 2) void ttt_fused(
    const float* __restrict__ lin, const float* __restrict__ dlt,
    float* __restrict__ W1, float* __restrict__ b1,
    float* __restrict__ W2, float* __restrict__ b2,
    float* __restrict__ abuf, float* __restrict__ Gbuf, int* __restrict__ bar)
{
  constexpr int R = 2 * P;            // rows per chunk (both batches)
  constexpr int RPT = R / 32;         // rows per thread in p1/p3
  constexpr int ST = R + 4;           // stride for transposed LDS tiles
  constexpr int SSTG = (R * 68 > 64 * ST) ? R * 68 : 64 * ST;
  constexpr float GS = 2.f / (float)R;
  constexpr float LR = 1e-3f;
  constexpr int NCC = (P == 64) ? 8 : 4;   // output cols per block in p2
  constexpr int RH  = (P == 64) ? 64 : 32; // rows handled per block in p2
  constexpr int KL  = (P == 64) ? 16 : 4;  // k4 iters per panel in p2

  __shared__ float sStage[SSTG];   // ci/a/G row panels [*][68]; ciT [64][ST]
  __shared__ float sW[1088];       // w1 panel / w2 col panel / w2 row panel
  __shared__ float sAT[16 * ST];   // a^T (own 16 hidden cols)
  __shared__ float sDZT[16 * ST];  // dZ^T (own 16 hidden cols)
  __shared__ float sRed[2048];     // reductions / partials

  const int bid = blockIdx.x;
  const int tid = threadIdx.x;
  const int j0 = bid * 16;                 // hidden slice base
  const int rg = tid >> 4;                 // p1/p3 row group
  const int jj = tid & 15;                 // p1/p3 hidden col
  const int c0 = (P == 64) ? ((bid & 127) * 8) : (bid * 4);
  const int rh = (P == 64) ? (bid >> 7) : 0;
  const int p2r = (P == 64) ? (tid >> 3) : ((tid >> 2) & 31);
  const int p2c = tid & (NCC - 1);
  const int ks  = (P == 64) ? 0 : (tid >> 7);
  const int rsB = tid >> 8;                // p3-B row half
  const int jbB = (tid >> 4) & 15;
  const int kbB = tid & 15;
  const int kkA = tid >> 3;                // p4a: k within panel
  const int jpA = (tid & 7) * 2;           // p4a: 2 hidden cols
  const int NB = gridDim.x;
  int ep = 0;

  for (int c = 0; c < NC; c++) {
    const int rb0 = c * P;
    const int rb1 = 2048 - P + c * P;

    // b2 snapshot for p2 (no b2 writer can be concurrent with this window)
    const float b2snap = b2[c0 + p2c];

    float zf[RPT];
    // ---------------- p1: z = ci@W1 + b1 ; a = gelu(z) ----------------
    {
      float zacc[RPT];
      #pragma unroll
      for (int i = 0; i < RPT; i++) zacc[i] = 0.f;
      for (int kp = 0; kp < 1024; kp += 64) {
        for (int q = tid; q < R * 16; q += 512) {
          const int r = q >> 4, k4 = (q & 15) << 2;
          const long grow = (r < P) ? (rb0 + r) : (rb1 + r);
          const float4 v = *(const float4*)&lin[grow * 1024 + kp + k4];
          *(float4*)&sStage[r * 68 + k4] = v;
        }
        {
          const int e = tid * 2;
          const int kk = e >> 4, j2 = e & 15;
          const float2 w = *(const float2*)&W1[(long)(kp + kk) * 4096 + j0 + j2];
          sW[kk * 16 + j2] = w.x;
          sW[kk * 16 + j2 + 1] = w.y;
        }
        __syncthreads();
        #pragma unroll 4
        for (int kk4 = 0; kk4 < 16; kk4++) {
          float w[4];
          #pragma unroll
          for (int q = 0; q < 4; q++) w[q] = sW[(kk4 * 4 + q) * 16 + jj];
          #pragma unroll
          for (int i = 0; i < RPT; i++) {
            const float4 c4 = *(const float4*)&sStage[(rg * RPT + i) * 68 + kk4 * 4];
            zacc[i] += c4.x * w[0] + c4.y * w[1] + c4.z * w[2] + c4.w * w[3];
          }
        }
        __syncthreads();
      }
      const float b1v = b1[j0 + jj];
      #pragma unroll
      for (int i = 0; i < RPT; i++) {
        const int r = rg * RPT + i;
        zf[i] = zacc[i] + b1v;
        const float a = gelu_f(zf[i]);
        sAT[jj * ST + r] = a;
        abuf[(long)r * 4096 + j0 + jj] = a;
      }
    }
    ++ep; grid_bar(bar, ep * NB);
    // ---------------- p2: pred = a@W2 + b2 -> G ----------------
    {
      float pacc = 0.f;
      for (int kp = 0; kp < 4096; kp += 64) {
        for (int q = tid; q < RH * 16; q += 512) {
          const int rl = q >> 4, k4 = (q & 15) << 2;
          const float4 v = *(const float4*)&abuf[(long)(rh * RH + rl) * 4096 + kp + k4];
          *(float4*)&sStage[rl * 68 + k4] = v;
        }
        if (tid < 64 * NCC) {
          const int kk = tid / NCC, cc2 = tid % NCC;
          sW[kk * NCC + cc2] = W2[(long)(kp + kk) * 1024 + c0 + cc2];
        }
        __syncthreads();
        const int kkb = (P == 64) ? 0 : (ks * 16);
        #pragma unroll 4
        for (int t4 = 0; t4 < KL; t4++) {
          const int kk = kkb + t4 * 4;
          const float4 a4 = *(const float4*)&sStage[p2r * 68 + kk];
          pacc += a4.x * sW[(kk + 0) * NCC + p2c] + a4.y * sW[(kk + 1) * NCC + p2c]
                + a4.z * sW[(kk + 2) * NCC + p2c] + a4.w * sW[(kk + 3) * NCC + p2c];
        }
        __syncthreads();
      }
      if (P == 16) {  // split-K reduce
        sRed[tid] = pacc;
        __syncthreads();
        if (ks == 0)
          pacc = sRed[tid] + sRed[tid + 128] + sRed[tid + 256] + sRed[tid + 384];
      }
      const bool act = (P == 64) || (ks == 0);
      float Gv = 0.f;
      if (act) {
        const int r = rh * RH + p2r;
        const long grow = (r < P) ? (rb0 + r) : (rb1 + r);
        const int col = c0 + p2c;
        const float tgt = lin[grow * 1024 + col]
                        + dlt[(long)(2 * c + (r >= P ? 1 : 0)) * 1024 + col];
        Gv = GS * (pacc + b2snap - tgt);
        Gbuf[(long)r * 1024 + col] = Gv;
      }
      __syncthreads();              // protect sRed reuse
      if (act) sRed[p2r * NCC + p2c] = Gv;
      __syncthreads();
      if (tid < NCC) {
        float s = 0.f;
        for (int rl = 0; rl < RH; rl++) s += sRed[rl * NCC + tid];
        atomicAdd(&b2[c0 + tid], -LR * s);
      }
    }
    ++ep; grid_bar(bar, ep * NB);
    // ---------------- p3: dZ = (G@W2^T)*gelu'(z), fused W2 row update ------
    {
      float dzacc[RPT];
      #pragma unroll
      for (int i = 0; i < RPT; i++) dzacc[i] = 0.f;
      for (int kp = 0; kp < 1024; kp += 64) {
        for (int q = tid; q < R * 16; q += 512) {
          const int r = q >> 4, k4 = (q & 15) << 2;
          const float4 v = *(const float4*)&Gbuf[(long)r * 1024 + kp + k4];
          *(float4*)&sStage[r * 68 + k4] = v;
        }
        {
          const int e = tid * 2;
          const int j2 = e >> 6, kk = e & 63;
          const float2 w = *(const float2*)&W2[(long)(j0 + j2) * 1024 + kp + kk];
          sW[j2 * 68 + kk] = w.x;
          sW[j2 * 68 + kk + 1] = w.y;
        }
        __syncthreads();
        // A: dZ partial (uses PRE-update W2 panel from LDS)
        #pragma unroll 4
        for (int kk4 = 0; kk4 < 16; kk4++) {
          const float4 w4 = *(const float4*)&sW[jj * 68 + kk4 * 4];
          #pragma unroll
          for (int i = 0; i < RPT; i++) {
            const float4 g4 = *(const float4*)&sStage[(rg * RPT + i) * 68 + kk4 * 4];
            dzacc[i] += g4.x * w4.x + g4.y * w4.y + g4.z * w4.z + g4.w * w4.w;
          }
        }
        // B: rank-R W2 row-panel update partials
        {
          float u0 = 0.f, u1 = 0.f, u2 = 0.f, u3 = 0.f;
          #pragma unroll 4
          for (int r = rsB * (R / 2); r < (rsB + 1) * (R / 2); r++) {
            const float av = sAT[jbB * ST + r];
            const float4 g4 = *(const float4*)&sStage[r * 68 + kbB * 4];
            u0 += av * g4.x; u1 += av * g4.y; u2 += av * g4.z; u3 += av * g4.w;
          }
          *(float4*)&sRed[rsB * 1024 + jbB * 64 + kbB * 4] = make_float4(u0, u1, u2, u3);
        }
        __syncthreads();
        {
          const int o = tid * 2;
          const int jb = o >> 6, kk = o & 63;
          const float2 v0 = *(const float2*)&sRed[o];
          const float2 v1 = *(const float2*)&sRed[1024 + o];
          float2 wv = *(const float2*)&sW[jb * 68 + kk];
          wv.x -= LR * (v0.x + v1.x);
          wv.y -= LR * (v0.y + v1.y);
          *(float2*)&W2[(long)(j0 + jb) * 1024 + kp + kk] = wv;
        }
        __syncthreads();
      }
      float bsum = 0.f;
      #pragma unroll
      for (int i = 0; i < RPT; i++) {
        const int r = rg * RPT + i;
        const float dz = dzacc[i] * gelu_grad_f(zf[i]);
        sDZT[jj * ST + r] = dz;
        bsum += dz;
      }
      sRed[rg * 16 + jj] = bsum;
      __syncthreads();
      if (tid < 16) {
        float s = 0.f;
        for (int g = 0; g < 32; g++) s += sRed[g * 16 + tid];
        b1[j0 + tid] -= LR * s;   // exclusive owner; read only by this block
      }
      __syncthreads();            // sDZT ready for p4a
    }
    // ---------------- p4a: W1 col-slice update ----------------
    {
      for (int kp = 0; kp < 1024; kp += 64) {
        for (int q = tid; q < R * 16; q += 512) {
          const int r = q >> 4, k4 = (q & 15) << 2;
          const long grow = (r < P) ? (rb0 + r) : (rb1 + r);
          const float4 v = *(const float4*)&lin[grow * 1024 + kp + k4];
          #pragma unroll
          for (int e = 0; e < 4; e++) {
            const int k = k4 + e;
            const int rx = r ^ ((k & 7) << 2);   // XOR swizzle (bank spread)
            sStage[k * ST + rx] = ((const float*)&v)[e];
          }
        }
        __syncthreads();
        float u0 = 0.f, u1 = 0.f;
        #pragma unroll 4
        for (int r4 = 0; r4 < R; r4 += 4) {
          const int rx = r4 ^ ((kkA & 7) << 2);
          const float4 c4 = *(const float4*)&sStage[kkA * ST + rx];
          const float4 d0 = *(const float4*)&sDZT[jpA * ST + r4];
          const float4 d1 = *(const float4*)&sDZT[(jpA + 1) * ST + r4];
          u0 += c4.x * d0.x + c4.y * d0.y + c4.z * d0.z + c4.w * d0.w;
          u1 += c4.x * d1.x + c4.y * d1.y + c4.z * d1.z + c4.w * d1.w;
        }
        float2 wv = *(const float2*)&W1[(long)(kp + kkA) * 4096 + j0 + jpA];
        wv.x -= LR * u0;
        wv.y -= LR * u1;
        *(float2*)&W1[(long)(kp + kkA) * 4096 + j0 + jpA] = wv;
        __syncthreads();
      }
    }
    // no grid barrier: next p1 touches only this block's W1/b1 slice + own
    // abuf cols; cross-block consumers are all behind the next p1->p2 barrier
  }
}

extern "C" void kernel_launch(void* const* d_in, const int* in_sizes, int n_in,
                              void* d_out, int out_size, void* d_ws, size_t ws_size,
                              hipStream_t stream) {
  const float* x     = (const float*)d_in[0];
  const float* teach = (const float*)d_in[1];
  const float* wq    = (const float*)d_in[2];
  const float* wk    = (const float*)d_in[3];
  const float* wv    = (const float*)d_in[4];
  const float* wo    = (const float*)d_in[5];
  float* out = (float*)d_out;
  float* ws  = (float*)d_ws;

  // ---- d_out layout (floats): cms_out, then the 8 updated params ----
  const long P_W1F = 4194304;
  const long P_B1F = 8388608;
  const long P_W2F = 8392704;
  const long P_B2F = 12587008;
  const long P_W1S = 12588032;
  const long P_B1S = 16782336;
  const long P_W2S = 16786432;
  const long P_B2S = 20980736;

  // ---- ws layout (floats) ----
  const long O_Q   = 0;
  const long O_K   = 4194304;
  const long O_V   = 8388608;
  const long O_CTX = 12582912;
  const long O_H   = 0;          // MLP hidden [4096,4096] (fwd; overlays QKV/CTX)
  const long O_AB  = 0;          // TTT abuf [R,4096]
  const long O_GB  = 524288;     // TTT Gbuf [R,1024]
  const long O_BAR = 12582912;   // TTT grid-barrier counter (dead CTX region)
  const long O_INF = 16787456;   // in_fast [4096,1024]
  const long O_INS = 20981760;   // in_slow [4096,1024]
  const long O_DF  = 25176064;   // 262,144
  const long O_DS  = 25438208;   // 65,536

  // --- seed fp32 masters directly into d_out (updated in place by TTT) ---
  {
    const long poff[8] = {P_W1F, P_B1F, P_W2F, P_B2F, P_W1S, P_B1S, P_W2S, P_B2S};
    const size_t psz[8] = {4194304, 4096, 4194304, 1024, 4194304, 4096, 4194304, 1024};
    for (int i = 0; i < 8; i++)
      hipMemcpyAsync(out + poff[i], d_in[6 + i], psz[i] * sizeof(float),
                     hipMemcpyDeviceToDevice, stream);
  }

  // --- per-chunk teach means ---
  compute_deltas<<<dim3(1281), 256, 0, stream>>>(teach, ws + O_DF, ws + O_DS);

  // --- Q/K/V projections ---
  {
    dim3 grd(16, 64);
    gemm_k<false, 0><<<grd, 256, 0, stream>>>(
        x, wq, ws + O_Q, nullptr, nullptr, 4096, 1024, 1024, 1024, 1024,
        4096, 0, 0, nullptr, 1, 0, 0, nullptr, 0.f);
    gemm_k<false, 0><<<grd, 256, 0, stream>>>(
        x, wk, ws + O_K, nullptr, nullptr, 4096, 1024, 1024, 1024, 1024,
        4096, 0, 0, nullptr, 1, 0, 0, nullptr, 0.f);
    gemm_k<false, 0><<<grd, 256, 0, stream>>>(
        x, wv, ws + O_V, nullptr, nullptr, 4096, 1024, 1024, 1024, 1024,
        4096, 0, 0, nullptr, 1, 0, 0, nullptr, 0.f);
  }

  // --- causal attention ---
  attn_kernel<<<dim3(32, 16, 2), 256, 0, stream>>>(ws + O_Q, ws + O_K, ws + O_V, ws + O_CTX);

  // --- in_fast = ctx @ wo ---
  gemm_k<false, 0><<<dim3(16, 64), 256, 0, stream>>>(
      ws + O_CTX, wo, ws + O_INF, nullptr, nullptr, 4096, 1024, 1024, 1024, 1024,
      4096, 0, 0, nullptr, 1, 0, 0, nullptr, 0.f);

  // --- MLP forwards with BASE params; full-width hidden buffer, 4 launches ---
  gemm_k<false, 1><<<dim3(64, 64), 256, 0, stream>>>(
      ws + O_INF, out + P_W1F, ws + O_H, nullptr, out + P_B1F,
      4096, 4096, 1024, 1024, 4096, 4096, 0, 0, nullptr, 1, 0, 0, nullptr, 0.f);
  gemm_k<false, 0><<<dim3(16, 64), 256, 0, stream>>>(
      ws + O_H, out + P_W2F, ws + O_INS, nullptr, out + P_B2F,
      4096, 1024, 4096, 4096, 1024, 4096, 0, 0, nullptr, 1, 0, 0, nullptr, 0.f);
  gemm_k<false, 1><<<dim3(64, 64), 256, 0, stream>>>(
      ws + O_INS, out + P_W1S, ws + O_H, nullptr, out + P_B1S,
      4096, 4096, 1024, 1024, 4096, 4096, 0, 0, nullptr, 1, 0, 0, nullptr, 0.f);
  gemm_k<false, 0><<<dim3(16, 64), 256, 0, stream>>>(
      ws + O_H, out + P_W2S, out, nullptr, out + P_B2S,
      4096, 1024, 4096, 4096, 1024, 4096, 0, 0, nullptr, 1, 0, 0, nullptr, 0.f);

  // --- TTT updates: ONE persistent kernel per level, own grid barrier ---
  hipMemsetAsync(ws + O_BAR, 0, 256, stream);
  {
    const float* linF = ws + O_INF;
    const float* dF   = ws + O_DF;
    ttt_fused<16, 128><<<dim3(256), dim3(512), 0, stream>>>(
        linF, dF, out + P_W1F, out + P_B1F, out + P_W2F, out + P_B2F,
        ws + O_AB, ws + O_GB, (int*)(ws + O_BAR));
  }
  hipMemsetAsync(ws + O_BAR, 0, 256, stream);
  {
    const float* linS = ws + O_INS;
    const float* dS   = ws + O_DS;
    ttt_fused<64, 32><<<dim3(256), dim3(512), 0, stream>>>(
        linS, dS, out + P_W1S, out + P_B1S, out + P_W2S, out + P_B2S,
        ws + O_AB, ws + O_GB, (int*)(ws + O_BAR));
  }
}